// Round 6
// baseline (370.913 us; speedup 1.0000x reference)
//
#include <hip/hip_runtime.h>

typedef __bf16 bf16;
typedef __bf16 bf16x4 __attribute__((ext_vector_type(4)));
typedef __bf16 bf16x8 __attribute__((ext_vector_type(8)));
typedef float f32x4 __attribute__((ext_vector_type(4)));

#define MFMA16(a, b, c) __builtin_amdgcn_mfma_f32_16x16x32_bf16((a), (b), (c), 0, 0, 0)

// Q pre-scale: 1/sqrt(64) * log2(e), so attention uses exp2 directly.
#define QSCALE 0.1803368808f

__device__ __forceinline__ void async_cp16(const bf16* g, bf16* l) {
    __builtin_amdgcn_global_load_lds((const __attribute__((address_space(1))) void*)g,
                                     (__attribute__((address_space(3))) void*)l, 16, 0, 0);
}

// ---------------- fused fp32 -> bf16 conversion (one launch, 7 tensors) ----
struct CvtArgs { const float* src[7]; bf16* dst[7]; };
__global__ void cvt_all(CvtArgs a) {
    int bx = blockIdx.x, t, off;
    if (bx < 12288) { t = bx >> 12;            off = bx & 4095; }
    else            { t = 3 + ((bx - 12288) >> 9); off = (bx - 12288) & 511; }
    size_t i = (size_t)off * 256 + threadIdx.x;
    const float4* p = (const float4*)(a.src[t] + i * 8);
    float4 x = p[0], y = p[1];
    bf16x8 o;
    o[0] = (bf16)x.x; o[1] = (bf16)x.y; o[2] = (bf16)x.z; o[3] = (bf16)x.w;
    o[4] = (bf16)y.x; o[5] = (bf16)y.y; o[6] = (bf16)y.z; o[7] = (bf16)y.w;
    *(bf16x8*)(a.dst[t] + i * 8) = o;
}

// ---------------- 128x128 GEMM core: 2-phase prefetch (minimum-T3 recipe) --
// BK=64. Double-buffered with STATIC buffer naming (unroll-by-2; r1's dynamic
// [cur] indexing doubled VALUBusy - avoided). Per step:
//   STAGE(next buf) | ds_read frags(cur) | MFMA | vmcnt(0) | s_barrier
// The vmcnt(0) drain sits AFTER the compute, so the 8 staged loads have the
// whole frag+MFMA phase (~250cy) to land - exposed latency ~0 instead of the
// full L2 latency the old __syncthreads-drain paid per step.
// WAR safety: step s's reads of buf(s&1) execute before its end barrier;
// step s+1's stage overwrites that buffer with LDS-writes landing >=300cy
// after the barrier.
// Swizzle (r2-proven, 0 conflicts): row=128B=8 chunks, both-sides c^(r&7).
// mode 0: Q -> bf16 [B,H,S,D], (acc+bias)*QSCALE; mode 1: K -> [B,H,S,D]
// mode 2: V^T -> [B,H,D,S'] token-permuted; mode 3: fp32 [M,1024]
__device__ __forceinline__ void gemm_core(
    const bf16* __restrict__ A, const bf16* __restrict__ W,
    const float* __restrict__ bias, void* __restrict__ Cout,
    int mode, int m0, int n0)
{
    __shared__ bf16 As0[128 * 64], As1[128 * 64];
    __shared__ bf16 Bs0[128 * 64], Bs1[128 * 64];
    const int K = 1024;
    const int tid = threadIdx.x;
    const int lane = tid & 63, wave = tid >> 6;
    const int l15 = lane & 15, quad = lane >> 4, l7 = l15 & 7;
    const int wm = wave >> 1, wn = wave & 1;

    f32x4 acc[4][4] = {};

    const int rb = tid >> 3;
    const int cg8 = ((tid & 7) ^ (rb & 7)) * 8;
    const bf16* Ag = A + (size_t)(m0 + rb) * K + cg8;
    const bf16* Wg = W + (size_t)(n0 + rb) * K + cg8;

    auto stageTo = [&](bf16* Al, bf16* Bl, int k0) {
#pragma unroll
        for (int j = 0; j < 4; ++j) {
            async_cp16(Ag + k0 + (size_t)(j * 32) * K, Al + tid * 8 + j * 2048);
            async_cp16(Wg + k0 + (size_t)(j * 32) * K, Bl + tid * 8 + j * 2048);
        }
    };

    auto step = [&](const bf16* Ac, const bf16* Bc, bf16* An, bf16* Bn,
                    int kn, bool doStage) {
        if (doStage) stageTo(An, Bn, kn);
#pragma unroll
        for (int ks = 0; ks < 2; ++ks) {
            bf16x8 af[4], bfr[4];
#pragma unroll
            for (int t = 0; t < 4; ++t) {
                const int sw = ((ks * 4 + quad) ^ l7) * 8;
                af[t]  = *(const bf16x8*)(Ac + (wm * 64 + t * 16 + l15) * 64 + sw);
                bfr[t] = *(const bf16x8*)(Bc + (wn * 64 + t * 16 + l15) * 64 + sw);
            }
#pragma unroll
            for (int mt = 0; mt < 4; ++mt)
#pragma unroll
                for (int nt = 0; nt < 4; ++nt)
                    acc[mt][nt] = MFMA16(af[mt], bfr[nt], acc[mt][nt]);
        }
        asm volatile("s_waitcnt vmcnt(0)" ::: "memory");
        __builtin_amdgcn_s_barrier();
    };

    // prologue: stage K-step 0 into buf0
    stageTo(As0, Bs0, 0);
    asm volatile("s_waitcnt vmcnt(0)" ::: "memory");
    __builtin_amdgcn_s_barrier();

    // 16 K-steps; step s consumes k=s*64 from buf(s&1), stages k=(s+1)*64
    for (int p = 0; p < 7; ++p) {
        step(As0, Bs0, As1, Bs1, p * 128 + 64, true);
        step(As1, Bs1, As0, Bs0, p * 128 + 128, true);
    }
    step(As0, Bs0, As1, Bs1, 960, true);    // step 14, stages last slice
    step(As1, Bs1, As0, Bs0, 0, false);     // step 15

    // epilogue
#pragma unroll
    for (int mt = 0; mt < 4; ++mt) {
#pragma unroll
        for (int nt = 0; nt < 4; ++nt) {
            int col = n0 + wn * 64 + nt * 16 + l15;
            float bcol = (mode == 2) ? 0.0f : bias[col];
#pragma unroll
            for (int r = 0; r < 4; ++r) {
                int row = m0 + wm * 64 + mt * 16 + quad * 4 + r;
                float val = acc[mt][nt][r];
                if (mode == 2) {
                    val += bias[row];
                    int bb = col >> 11, s = col & 2047;
                    int u = s & 31;
                    int sp = (s & ~31) | (((u >> 2) & 3) * 8 + (u >> 4) * 4 + (u & 3));
                    ((bf16*)Cout)[((size_t)(bb * 1024 + row) << 11) + sp] = (bf16)val;
                } else if (mode == 3) {
                    ((float*)Cout)[(size_t)row * 1024 + col] = val + bcol;
                } else {
                    val += bcol;
                    if (mode == 0) val *= QSCALE;
                    int bb = row >> 11, s = row & 2047, hh = col >> 6, d = col & 63;
                    ((bf16*)Cout)[(((size_t)(bb * 16 + hh) * 2048 + s) << 6) + d] = (bf16)val;
                }
            }
        }
    }
}

struct QkvArgs {
    const bf16* A[3];
    const bf16* W[3];
    const float* bias[3];
    bf16* out[3];
};

// grid (512, 3). XCD/L2-aware remap (r5-proven: FETCH 99.5 -> 49.4 MB):
// the 8 blocks sharing an A-row-panel (z<2) / Xv-col-panel (z=2) land on
// consecutive per-XCD slots of ONE XCD.
__global__ __launch_bounds__(256) void qkv_gemm(QkvArgs t) {
    int z = blockIdx.y;
    int bid = blockIdx.x;
    int lo = bid & 7, mid = (bid >> 3) & 7, hi = bid >> 6;
    int m0, n0;
    if (z < 2) { m0 = (lo + hi * 8) * 128; n0 = mid * 128; }
    else       { m0 = mid * 128;           n0 = (lo + hi * 8) * 128; }
    gemm_core(t.A[z], t.W[z], t.bias[z], t.out[z], z, m0, n0);
}

// O-projection: fp32 out, 128^2 core
__global__ __launch_bounds__(256) void oproj_gemm(
    const bf16* __restrict__ A, const bf16* __restrict__ W,
    const float* __restrict__ bias, float* __restrict__ Cout) {
    gemm_core(A, W, bias, Cout, 3, blockIdx.x * 128, blockIdx.y * 128);
}

// ---------------- flash attention: S^T trick, full-rate PV, 2-phase -------
// 1D grid 512 (r5 remap: all 8 q-tiles of a (b,h) share one XCD; per-XCD K/V
// = 4MB = L2). Same 2-phase prefetch recipe as gemm_core: stage next K/V tile
// at step top into the other (statically named) buffer, drain vmcnt(0) after
// the S^T+softmax+PV compute.
__global__ __launch_bounds__(256, 2) void attn_kernel(
    const bf16* __restrict__ Qh, const bf16* __restrict__ Kh,
    const bf16* __restrict__ Vtg, bf16* __restrict__ AO)
{
    __shared__ bf16 Kl0[64 * 64], Kl1[64 * 64];   // [key][d], chunk c holds src c^(key&7)
    __shared__ bf16 Vl0[64 * 64], Vl1[64 * 64];   // [d][key'], chunk c holds src c^(d&7)

    const int tid = threadIdx.x;
    const int lane = tid & 63, wave = tid >> 6;
    const int l15 = lane & 15, quad = lane >> 4, l7 = l15 & 7;
    const int g = blockIdx.x & 63, qi = blockIdx.x >> 6;
    const int h = g & 15, b = g >> 4;
    const size_t base = (size_t)(b * 16 + h) << 17;   // * 2048 * 64
    const int q0 = qi * 256 + wave * 64;

    // Q fragments (pre-scaled by QSCALE): B operand of S^T
    bf16x8 qf[4][2];
#pragma unroll
    for (int qt = 0; qt < 4; ++qt)
#pragma unroll
        for (int ks = 0; ks < 2; ++ks)
            qf[qt][ks] = *(const bf16x8*)(Qh + base + (q0 + qt * 16 + l15) * 64 + ks * 32 + quad * 8);

    f32x4 o[4][4] = {};   // O^T tiles: [dt][qt], lane l15=q, rows d=quad*4+r
    float ls[4] = {};     // per-q partial row sums (q = l15)

    const int sr = tid >> 3;
    const int sc0 = ((tid & 7) ^ (sr & 7)) * 8;
    const int sr2 = sr + 32;

    auto stageTo = [&](bf16* Kn, bf16* Vn, int kt) {
        async_cp16(Kh + base + (size_t)(kt + sr) * 64 + sc0, Kn + tid * 8);
        async_cp16(Kh + base + (size_t)(kt + sr2) * 64 + sc0, Kn + (tid + 256) * 8);
        async_cp16(Vtg + base + (size_t)sr * 2048 + kt + sc0, Vn + tid * 8);
        async_cp16(Vtg + base + (size_t)sr2 * 2048 + kt + sc0, Vn + (tid + 256) * 8);
    };

    auto step = [&](const bf16* Kc, const bf16* Vc, bf16* Kn, bf16* Vn,
                    int ktn, bool doStage) {
        if (doStage) stageTo(Kn, Vn, ktn);

        // ---- K fragments (A operand of S^T) ----
        bf16x8 kb[2][4];
#pragma unroll
        for (int ks = 0; ks < 2; ++ks)
#pragma unroll
            for (int ktile = 0; ktile < 4; ++ktile)
                kb[ks][ktile] = *(const bf16x8*)(Kc + (ktile * 16 + l15) * 64 + (((ks * 4 + quad) ^ l7) * 8));

        // ---- S^T = K.Q^T, exp2, pack pairs of 16-key tiles into PV B-operand ----
        bf16x8 pf[4][2];
#pragma unroll
        for (int qt = 0; qt < 4; ++qt) {
            f32x4 sc[4] = {};
#pragma unroll
            for (int ks = 0; ks < 2; ++ks)
#pragma unroll
                for (int ktile = 0; ktile < 4; ++ktile)
                    sc[ktile] = MFMA16(kb[ks][ktile], qf[qt][ks], sc[ktile]);
            float sum = 0.0f;
#pragma unroll
            for (int kc = 0; kc < 2; ++kc) {
                bf16x8 pk;
#pragma unroll
                for (int t = 0; t < 2; ++t)
#pragma unroll
                    for (int r = 0; r < 4; ++r) {
                        float p = __builtin_amdgcn_exp2f(sc[kc * 2 + t][r]);
                        sum += p;
                        pk[t * 4 + r] = (bf16)p;
                    }
                pf[qt][kc] = pk;
            }
            ls[qt] += sum;
        }

        // ---- V^T fragments (A operand of PV) ----
        bf16x8 va[4][2];
#pragma unroll
        for (int dt = 0; dt < 4; ++dt)
#pragma unroll
            for (int kc = 0; kc < 2; ++kc)
                va[dt][kc] = *(const bf16x8*)(Vc + (dt * 16 + l15) * 64 + (((kc * 4 + quad) ^ l7) * 8));

        // ---- O^T += V^T . P^T ----
#pragma unroll
        for (int dt = 0; dt < 4; ++dt)
#pragma unroll
            for (int qt = 0; qt < 4; ++qt)
#pragma unroll
                for (int kc = 0; kc < 2; ++kc)
                    o[dt][qt] = MFMA16(va[dt][kc], pf[qt][kc], o[dt][qt]);

        asm volatile("s_waitcnt vmcnt(0)" ::: "memory");
        __builtin_amdgcn_s_barrier();
    };

    // prologue: stage tile 0 into buf0
    stageTo(Kl0, Vl0, 0);
    asm volatile("s_waitcnt vmcnt(0)" ::: "memory");
    __builtin_amdgcn_s_barrier();

    // 32 key-tiles; tile t consumes buf(t&1), stages tile t+1
    for (int p = 0; p < 15; ++p) {
        step(Kl0, Vl0, Kl1, Vl1, p * 128 + 64, true);
        step(Kl1, Vl1, Kl0, Vl0, p * 128 + 128, true);
    }
    step(Kl0, Vl0, Kl1, Vl1, 1984, true);   // tile 30, stages tile 31
    step(Kl1, Vl1, Kl0, Vl0, 0, false);     // tile 31

    // epilogue: reduce l across quads (same q lives at l15, +16, +32, +48)
#pragma unroll
    for (int qt = 0; qt < 4; ++qt) {
        float l = ls[qt];
        l += __shfl_xor(l, 16, 64);
        l += __shfl_xor(l, 32, 64);
        float inv = 1.0f / l;
        size_t rb = ((size_t)(b * 2048 + q0 + qt * 16 + l15)) * 1024 + h * 64;
#pragma unroll
        for (int dt = 0; dt < 4; ++dt) {
            bf16x4 ov = {(bf16)(o[dt][qt][0] * inv), (bf16)(o[dt][qt][1] * inv),
                         (bf16)(o[dt][qt][2] * inv), (bf16)(o[dt][qt][3] * inv)};
            *(bf16x4*)(AO + rb + dt * 16 + quad * 4) = ov;
        }
    }
}

// ---------------- host ----------------
extern "C" void kernel_launch(void* const* d_in, const int* in_sizes, int n_in,
                              void* d_out, int out_size, void* d_ws, size_t ws_size,
                              hipStream_t stream) {
    const float* q  = (const float*)d_in[0];
    const float* k  = (const float*)d_in[1];
    const float* v  = (const float*)d_in[2];
    const float* Wq = (const float*)d_in[3];
    const float* bq = (const float*)d_in[4];
    const float* Wk = (const float*)d_in[5];
    const float* bk = (const float*)d_in[6];
    const float* Wv = (const float*)d_in[7];
    const float* bv = (const float*)d_in[8];
    const float* Wo = (const float*)d_in[9];
    const float* bo = (const float*)d_in[10];
    float* out = (float*)d_out;

    const size_t NX = (size_t)8192 * 1024;
    const size_t NW = (size_t)1024 * 1024;
    bf16* ws  = (bf16*)d_ws;
    bf16* Xq  = ws;            // reused as AO after projections
    bf16* Xk  = Xq + NX;
    bf16* Xv  = Xk + NX;
    bf16* Wqb = Xv + NX;
    bf16* Wkb = Wqb + NW;
    bf16* Wvb = Wkb + NW;
    bf16* Wob = Wvb + NW;
    bf16* Qh  = Wob + NW;      // [B,H,S,D], pre-scaled by QSCALE
    bf16* Kh  = Qh + NX;       // [B,H,S,D]
    bf16* Vt  = Kh + NX;       // [B,H,D,S'] (tokens permuted within 32-groups)
    bf16* AO  = Xq;

    CvtArgs ca;
    ca.src[0] = q;  ca.dst[0] = Xq;
    ca.src[1] = k;  ca.dst[1] = Xk;
    ca.src[2] = v;  ca.dst[2] = Xv;
    ca.src[3] = Wq; ca.dst[3] = Wqb;
    ca.src[4] = Wk; ca.dst[4] = Wkb;
    ca.src[5] = Wv; ca.dst[5] = Wvb;
    ca.src[6] = Wo; ca.dst[6] = Wob;
    cvt_all<<<14336, 256, 0, stream>>>(ca);

    QkvArgs t;
    t.A[0] = Xq;  t.W[0] = Wqb; t.bias[0] = bq; t.out[0] = Qh;
    t.A[1] = Xk;  t.W[1] = Wkb; t.bias[1] = bk; t.out[1] = Kh;
    t.A[2] = Wvb; t.W[2] = Xv;  t.bias[2] = bv; t.out[2] = Vt;   // V^T: A=Wv, W=Xv
    qkv_gemm<<<dim3(512, 3), dim3(256, 1, 1), 0, stream>>>(t);

    attn_kernel<<<512, 256, 0, stream>>>(Qh, Kh, Vt, AO);

    oproj_gemm<<<dim3(64, 8), dim3(256, 1, 1), 0, stream>>>(AO, Wob, bo, out);
}

// Round 7
// 340.494 us; speedup vs baseline: 1.0893x; 1.0893x over previous
//
#include <hip/hip_runtime.h>

typedef __bf16 bf16;
typedef __bf16 bf16x4 __attribute__((ext_vector_type(4)));
typedef __bf16 bf16x8 __attribute__((ext_vector_type(8)));
typedef float f32x4 __attribute__((ext_vector_type(4)));

#define MFMA16(a, b, c) __builtin_amdgcn_mfma_f32_16x16x32_bf16((a), (b), (c), 0, 0, 0)

// Q pre-scale: 1/sqrt(64) * log2(e), so attention uses exp2 directly.
#define QSCALE 0.1803368808f

__device__ __forceinline__ void async_cp16(const bf16* g, bf16* l) {
    __builtin_amdgcn_global_load_lds((const __attribute__((address_space(1))) void*)g,
                                     (__attribute__((address_space(3))) void*)l, 16, 0, 0);
}

// ---------------- fused fp32 -> bf16 conversion (one launch, 7 tensors) ----
struct CvtArgs { const float* src[7]; bf16* dst[7]; };
__global__ void cvt_all(CvtArgs a) {
    int bx = blockIdx.x, t, off;
    if (bx < 12288) { t = bx >> 12;            off = bx & 4095; }
    else            { t = 3 + ((bx - 12288) >> 9); off = (bx - 12288) & 511; }
    size_t i = (size_t)off * 256 + threadIdx.x;
    const float4* p = (const float4*)(a.src[t] + i * 8);
    float4 x = p[0], y = p[1];
    bf16x8 o;
    o[0] = (bf16)x.x; o[1] = (bf16)x.y; o[2] = (bf16)x.z; o[3] = (bf16)x.w;
    o[4] = (bf16)y.x; o[5] = (bf16)y.y; o[6] = (bf16)y.z; o[7] = (bf16)y.w;
    *(bf16x8*)(a.dst[t] + i * 8) = o;
}

// ---------------- 128x128 GEMM core (r5-proven: qkv 95.6us, 0 conflicts) --
// BK=64, single-buffered. Row = 128B = 8 chunks; both-sides swizzle c^(r&7).
// (2-phase prefetch variants tested r1/r6: net-negative on this structure —
// the barrier drain is covered by inter-block TLP at 5 blocks/CU; dbuf halves
// that TLP for nothing. Do not revisit without a full 8-phase port.)
// mode 0: Q -> bf16 [B,H,S,D], (acc+bias)*QSCALE; mode 1: K -> [B,H,S,D]
// mode 2: V^T -> [B,H,D,S'] token-permuted; mode 3: fp32 [M,1024]
__device__ __forceinline__ void gemm_core(
    const bf16* __restrict__ A, const bf16* __restrict__ W,
    const float* __restrict__ bias, void* __restrict__ Cout,
    int mode, int m0, int n0)
{
    __shared__ bf16 As[128 * 64];
    __shared__ bf16 Bs[128 * 64];
    const int K = 1024;
    const int tid = threadIdx.x;
    const int lane = tid & 63, wave = tid >> 6;
    const int l15 = lane & 15, quad = lane >> 4, l7 = l15 & 7;
    const int wm = wave >> 1, wn = wave & 1;

    f32x4 acc[4][4] = {};

    const int rb = tid >> 3;
    const int cg8 = ((tid & 7) ^ (rb & 7)) * 8;
    const bf16* Ag = A + (size_t)(m0 + rb) * K + cg8;
    const bf16* Wg = W + (size_t)(n0 + rb) * K + cg8;
    bf16* Al = As + tid * 8;
    bf16* Bl = Bs + tid * 8;

    for (int k0 = 0; k0 < K; k0 += 64) {
        __syncthreads();
#pragma unroll
        for (int j = 0; j < 4; ++j) {
            async_cp16(Ag + k0 + (size_t)(j * 32) * K, Al + j * 2048);
            async_cp16(Wg + k0 + (size_t)(j * 32) * K, Bl + j * 2048);
        }
        __syncthreads();

#pragma unroll
        for (int ks = 0; ks < 2; ++ks) {
            bf16x8 af[4], bfr[4];
#pragma unroll
            for (int t = 0; t < 4; ++t) {
                const int sw = ((ks * 4 + quad) ^ l7) * 8;
                af[t]  = *(const bf16x8*)(As + (wm * 64 + t * 16 + l15) * 64 + sw);
                bfr[t] = *(const bf16x8*)(Bs + (wn * 64 + t * 16 + l15) * 64 + sw);
            }
#pragma unroll
            for (int mt = 0; mt < 4; ++mt)
#pragma unroll
                for (int nt = 0; nt < 4; ++nt)
                    acc[mt][nt] = MFMA16(af[mt], bfr[nt], acc[mt][nt]);
        }
    }

#pragma unroll
    for (int mt = 0; mt < 4; ++mt) {
#pragma unroll
        for (int nt = 0; nt < 4; ++nt) {
            int col = n0 + wn * 64 + nt * 16 + l15;
            float bcol = (mode == 2) ? 0.0f : bias[col];
#pragma unroll
            for (int r = 0; r < 4; ++r) {
                int row = m0 + wm * 64 + mt * 16 + quad * 4 + r;
                float val = acc[mt][nt][r];
                if (mode == 2) {
                    val += bias[row];
                    int bb = col >> 11, s = col & 2047;
                    int u = s & 31;
                    int sp = (s & ~31) | (((u >> 2) & 3) * 8 + (u >> 4) * 4 + (u & 3));
                    ((bf16*)Cout)[((size_t)(bb * 1024 + row) << 11) + sp] = (bf16)val;
                } else if (mode == 3) {
                    ((float*)Cout)[(size_t)row * 1024 + col] = val + bcol;
                } else {
                    val += bcol;
                    if (mode == 0) val *= QSCALE;
                    int bb = row >> 11, s = row & 2047, hh = col >> 6, d = col & 63;
                    ((bf16*)Cout)[(((size_t)(bb * 16 + hh) * 2048 + s) << 6) + d] = (bf16)val;
                }
            }
        }
    }
}

struct QkvArgs {
    const bf16* A[3];
    const bf16* W[3];
    const float* bias[3];
    bf16* out[3];
};

// grid (512, 3). XCD/L2-aware remap (r5-proven: FETCH 99.5 -> 49.4 MB).
__global__ __launch_bounds__(256) void qkv_gemm(QkvArgs t) {
    int z = blockIdx.y;
    int bid = blockIdx.x;
    int lo = bid & 7, mid = (bid >> 3) & 7, hi = bid >> 6;
    int m0, n0;
    if (z < 2) { m0 = (lo + hi * 8) * 128; n0 = mid * 128; }
    else       { m0 = mid * 128;           n0 = (lo + hi * 8) * 128; }
    gemm_core(t.A[z], t.W[z], t.bias[z], t.out[z], z, m0, n0);
}

// O-projection: fp32 out, 128^2 core
__global__ __launch_bounds__(256) void oproj_gemm(
    const bf16* __restrict__ A, const bf16* __restrict__ W,
    const float* __restrict__ bias, float* __restrict__ Cout) {
    gemm_core(A, W, bias, Cout, 3, blockIdx.x * 128, blockIdx.y * 128);
}

// ---------------- flash attention: S^T trick, full-rate PV ----------------
// r6 post-mortem: attn was GRID-limited (512 blocks = 2 blocks/CU = 18% occ;
// per-wave serial MFMA+softmax chains can't overlap with so few waves).
// Fix: 32 q-rows/wave (was 64). Block = 4 waves = 128 q-rows; grid = 64
// groups x 16 q-tiles = 1024 blocks = 4 blocks/CU -> 50% occupancy ceiling.
// Total MFMA/exp2 work unchanged; per-wave chains halve; 2x waves hide them.
// K/V staged 16x per group (was 8x) — L2 hits after the XCD remap (g=bid&63
// keeps all q-tiles of a (b,h) on one XCD; per-XCD K/V = 4MB = L2).
// Staging reverted to r5 single-buffer __syncthreads (2-phase regressed, r6).
// S^T = K.Q^T; V^T token-permuted to match PV B-operand layout.
__global__ __launch_bounds__(256, 4) void attn_kernel(
    const bf16* __restrict__ Qh, const bf16* __restrict__ Kh,
    const bf16* __restrict__ Vtg, bf16* __restrict__ AO)
{
    __shared__ bf16 Kl[64 * 64];   // [key][d], 16B chunk c holds src chunk c^(key&7)
    __shared__ bf16 Vl[64 * 64];   // [d][key'], 16B chunk c holds src chunk c^(d&7)

    const int tid = threadIdx.x;
    const int lane = tid & 63, wave = tid >> 6;
    const int l15 = lane & 15, quad = lane >> 4, l7 = l15 & 7;
    const int g = blockIdx.x & 63, qi = blockIdx.x >> 6;
    const int h = g & 15, b = g >> 4;
    const size_t base = (size_t)(b * 16 + h) << 17;   // * 2048 * 64
    const int q0 = qi * 128 + wave * 32;

    // Q fragments (pre-scaled by QSCALE): B operand of S^T. 2 tiles of 16 q.
    bf16x8 qf[2][2];
#pragma unroll
    for (int qt = 0; qt < 2; ++qt)
#pragma unroll
        for (int ks = 0; ks < 2; ++ks)
            qf[qt][ks] = *(const bf16x8*)(Qh + base + (q0 + qt * 16 + l15) * 64 + ks * 32 + quad * 8);

    f32x4 o[4][2] = {};   // O^T tiles: [dt][qt], lane l15=q, rows d=quad*4+r
    float ls[2] = {};     // per-q partial row sums (q = l15)

    const int sr = tid >> 3;
    const int sc0 = ((tid & 7) ^ (sr & 7)) * 8;
    const int sr2 = sr + 32;

    for (int kt = 0; kt < 2048; kt += 64) {
        __syncthreads();
        async_cp16(Kh + base + (size_t)(kt + sr) * 64 + sc0, Kl + tid * 8);
        async_cp16(Kh + base + (size_t)(kt + sr2) * 64 + sc0, Kl + (tid + 256) * 8);
        async_cp16(Vtg + base + (size_t)sr * 2048 + kt + sc0, Vl + tid * 8);
        async_cp16(Vtg + base + (size_t)sr2 * 2048 + kt + sc0, Vl + (tid + 256) * 8);
        __syncthreads();

        // ---- K fragments (A operand of S^T) ----
        bf16x8 kb[2][4];
#pragma unroll
        for (int ks = 0; ks < 2; ++ks)
#pragma unroll
            for (int ktile = 0; ktile < 4; ++ktile)
                kb[ks][ktile] = *(const bf16x8*)(Kl + (ktile * 16 + l15) * 64 + (((ks * 4 + quad) ^ l7) * 8));

        // ---- S^T = K.Q^T, exp2, pack pairs of 16-key tiles into PV B-operand ----
        bf16x8 pf[2][2];   // [qt][kc]: keys kc*32 + quad*8 + {0..7} (V' ordering)
#pragma unroll
        for (int qt = 0; qt < 2; ++qt) {
            f32x4 sc[4] = {};
#pragma unroll
            for (int ks = 0; ks < 2; ++ks)
#pragma unroll
                for (int ktile = 0; ktile < 4; ++ktile)
                    sc[ktile] = MFMA16(kb[ks][ktile], qf[qt][ks], sc[ktile]);
            float sum = 0.0f;
#pragma unroll
            for (int kc = 0; kc < 2; ++kc) {
                bf16x8 pk;
#pragma unroll
                for (int t = 0; t < 2; ++t)
#pragma unroll
                    for (int r = 0; r < 4; ++r) {
                        float p = __builtin_amdgcn_exp2f(sc[kc * 2 + t][r]);
                        sum += p;
                        pk[t * 4 + r] = (bf16)p;
                    }
                pf[qt][kc] = pk;
            }
            ls[qt] += sum;
        }

        // ---- V^T fragments (A operand of PV): d=l15 row, keys kc*32+quad*8+{0..7} ----
        bf16x8 va[4][2];
#pragma unroll
        for (int dt = 0; dt < 4; ++dt)
#pragma unroll
            for (int kc = 0; kc < 2; ++kc)
                va[dt][kc] = *(const bf16x8*)(Vl + (dt * 16 + l15) * 64 + (((kc * 4 + quad) ^ l7) * 8));

        // ---- O^T += V^T . P^T (full-rate 16x16x32) ----
#pragma unroll
        for (int dt = 0; dt < 4; ++dt)
#pragma unroll
            for (int qt = 0; qt < 2; ++qt)
#pragma unroll
                for (int kc = 0; kc < 2; ++kc)
                    o[dt][qt] = MFMA16(va[dt][kc], pf[qt][kc], o[dt][qt]);
    }

    // epilogue: reduce l across quads (same q lives at l15, +16, +32, +48)
#pragma unroll
    for (int qt = 0; qt < 2; ++qt) {
        float l = ls[qt];
        l += __shfl_xor(l, 16, 64);
        l += __shfl_xor(l, 32, 64);
        float inv = 1.0f / l;
        size_t rb = ((size_t)(b * 2048 + q0 + qt * 16 + l15)) * 1024 + h * 64;
#pragma unroll
        for (int dt = 0; dt < 4; ++dt) {
            bf16x4 ov = {(bf16)(o[dt][qt][0] * inv), (bf16)(o[dt][qt][1] * inv),
                         (bf16)(o[dt][qt][2] * inv), (bf16)(o[dt][qt][3] * inv)};
            *(bf16x4*)(AO + rb + dt * 16 + quad * 4) = ov;
        }
    }
}

// ---------------- host ----------------
extern "C" void kernel_launch(void* const* d_in, const int* in_sizes, int n_in,
                              void* d_out, int out_size, void* d_ws, size_t ws_size,
                              hipStream_t stream) {
    const float* q  = (const float*)d_in[0];
    const float* k  = (const float*)d_in[1];
    const float* v  = (const float*)d_in[2];
    const float* Wq = (const float*)d_in[3];
    const float* bq = (const float*)d_in[4];
    const float* Wk = (const float*)d_in[5];
    const float* bk = (const float*)d_in[6];
    const float* Wv = (const float*)d_in[7];
    const float* bv = (const float*)d_in[8];
    const float* Wo = (const float*)d_in[9];
    const float* bo = (const float*)d_in[10];
    float* out = (float*)d_out;

    const size_t NX = (size_t)8192 * 1024;
    const size_t NW = (size_t)1024 * 1024;
    bf16* ws  = (bf16*)d_ws;
    bf16* Xq  = ws;            // reused as AO after projections
    bf16* Xk  = Xq + NX;
    bf16* Xv  = Xk + NX;
    bf16* Wqb = Xv + NX;
    bf16* Wkb = Wqb + NW;
    bf16* Wvb = Wkb + NW;
    bf16* Wob = Wvb + NW;
    bf16* Qh  = Wob + NW;      // [B,H,S,D], pre-scaled by QSCALE
    bf16* Kh  = Qh + NX;       // [B,H,S,D]
    bf16* Vt  = Kh + NX;       // [B,H,D,S'] (tokens permuted within 32-groups)
    bf16* AO  = Xq;

    CvtArgs ca;
    ca.src[0] = q;  ca.dst[0] = Xq;
    ca.src[1] = k;  ca.dst[1] = Xk;
    ca.src[2] = v;  ca.dst[2] = Xv;
    ca.src[3] = Wq; ca.dst[3] = Wqb;
    ca.src[4] = Wk; ca.dst[4] = Wkb;
    ca.src[5] = Wv; ca.dst[5] = Wvb;
    ca.src[6] = Wo; ca.dst[6] = Wob;
    cvt_all<<<14336, 256, 0, stream>>>(ca);

    QkvArgs t;
    t.A[0] = Xq;  t.W[0] = Wqb; t.bias[0] = bq; t.out[0] = Qh;
    t.A[1] = Xk;  t.W[1] = Wkb; t.bias[1] = bk; t.out[1] = Kh;
    t.A[2] = Wvb; t.W[2] = Xv;  t.bias[2] = bv; t.out[2] = Vt;   // V^T: A=Wv, W=Xv
    qkv_gemm<<<dim3(512, 3), dim3(256, 1, 1), 0, stream>>>(t);

    attn_kernel<<<1024, 256, 0, stream>>>(Qh, Kh, Vt, AO);

    oproj_gemm<<<dim3(64, 8), dim3(256, 1, 1), 0, stream>>>(AO, Wob, bo, out);
}